// Round 5
// baseline (375.457 us; speedup 1.0000x reference)
//
#include <hip/hip_runtime.h>

// Per-voxel LUT gather + scale + onehot, all float32.
//   out[i]     = paren[i] * scale(lab[i]), scale(0) == 1.0  (bg bit-exact)
//   onehot ch0 = lab==0, ch1 = dark vessel, ch2 = bright vessel
//
// R10: channel-segmented grid ("stream phasing"). Evidence: R8 3x-diagnostic
// measured this kernel at 4.1 TB/s HBM (write rate 3.3 TB/s concurrent with
// reads) vs the poison-fill's 6.6 TB/s single-stream write-only; R6->R7
// burst-length doubling was null; R9 plain stores regressed 8 us (L2 thrash)
// -> the deficit is the 6-simultaneous-DRAM-streams R/W mix itself.
// Fix: 4 grid segments of 4096 blocks. Seg 0: read labels+paren, write
// scaled out (copy-like, 2 read + 1 write stream). Segs 1-3: read labels
// (L3-resident after seg 0 - R8 showed NT loads allocate L3; NT stores
// don't pollute it), write ONE onehot channel (fill-like, 1 write stream).
// Blocks dispatch ~in order -> chip-wide phases with 1-2 live DRAM streams
// instead of 6. Extra cost: 3x label re-reads at L3 BW (~6 us), 4x label
// decode VALU (5% -> ~20%, irrelevant). NT loads + NT stores (R9: plain
// stores -8 us). R7 16-voxel wave-burst addressing kept within segments.

constexpr unsigned int VOX = 256u * 256u * 256u;  // 16,777,216
constexpr int N_IDS = 256;

typedef int   vint4  __attribute__((ext_vector_type(4)));
typedef float vflt4  __attribute__((ext_vector_type(4)));

__global__ __launch_bounds__(256)
void synth_semantic_kernel(const int* __restrict__ labels,
                           const float* __restrict__ id_intensity,
                           const int* __restrict__ id_is_dark,
                           const float* __restrict__ paren,
                           float* __restrict__ out)
{
    // LUT: bits[30:0] = f32 scale (id 0 forced to 1.0; scale in (0,2) so the
    // sign bit is free), bit 31 = dark flag.
    __shared__ unsigned int lut[N_IDS];
    const int t = threadIdx.x;
    {
        float sc = (t == 0) ? 1.0f : id_intensity[t];
        union { float f; unsigned int u; } cv; cv.f = sc;
        lut[t] = (cv.u & 0x7FFFFFFFu) | ((id_is_dark[t] == 1) ? 0x80000000u : 0u);
    }
    __syncthreads();

    // seg 0: scaled out; seg 1: bg; seg 2: dark; seg 3: bright.
    const unsigned int seg   = blockIdx.x >> 12;          // 0..3
    const unsigned int chunk = blockIdx.x & 4095u;        // block within segment
    const unsigned int lane  = (unsigned int)t & 63u;
    const unsigned int wave  = chunk * 4u + ((unsigned int)t >> 6);  // 0..16383
    const unsigned int base  = wave * 1024u + lane * 4u;

    // Labels: 4 x 1 KB wave-contiguous NT loads (16 voxels/thread).
    vint4 l[4];
#pragma unroll
    for (int g = 0; g < 4; ++g)
        l[g] = __builtin_nontemporal_load((const vint4*)(labels + base + 256u * g));

    if (seg == 0) {
        // out = paren * scale(lab); bg keeps *1.0f (bit-exact).
        vflt4 p[4];
#pragma unroll
        for (int g = 0; g < 4; ++g)
            p[g] = __builtin_nontemporal_load((const vflt4*)(paren + base + 256u * g));
#pragma unroll
        for (int g = 0; g < 4; ++g) {
            const int   labs[4] = {l[g].x, l[g].y, l[g].z, l[g].w};
            const float pv[4]   = {p[g].x, p[g].y, p[g].z, p[g].w};
            float oo[4];
#pragma unroll
            for (int j = 0; j < 4; ++j) {
                union { unsigned int u; float f; } sc;
                sc.u = lut[labs[j]] & 0x7FFFFFFFu;
                oo[j] = pv[j] * sc.f;
            }
            const vflt4 v = (vflt4){oo[0], oo[1], oo[2], oo[3]};
            __builtin_nontemporal_store(v, (vflt4*)(out + base + 256u * g));
        }
    } else {
        // One onehot channel from labels alone.
#pragma unroll
        for (int g = 0; g < 4; ++g) {
            const int labs[4] = {l[g].x, l[g].y, l[g].z, l[g].w};
            float oo[4];
#pragma unroll
            for (int j = 0; j < 4; ++j) {
                const int lab = labs[j];
                const unsigned int darkbit = lut[lab] >> 31;
                bool f;
                if (seg == 1)      f = (lab == 0);
                else if (seg == 2) f = (lab != 0) && darkbit;
                else               f = (lab != 0) && !darkbit;
                oo[j] = f ? 1.0f : 0.0f;
            }
            const vflt4 v = (vflt4){oo[0], oo[1], oo[2], oo[3]};
            __builtin_nontemporal_store(v, (vflt4*)(out + seg * VOX + base + 256u * g));
        }
    }
}

extern "C" void kernel_launch(void* const* d_in, const int* in_sizes, int n_in,
                              void* d_out, int out_size, void* d_ws, size_t ws_size,
                              hipStream_t stream) {
    const int*   labels  = (const int*)d_in[0];
    const float* id_int  = (const float*)d_in[1];
    const int*   id_dark = (const int*)d_in[2];
    const float* paren   = (const float*)d_in[3];
    float*       outp    = (float*)d_out;

    // 4 segments x 4096 blocks; each block covers 4096 voxels of one channel.
    const unsigned int blocks = 4u * ((VOX / 16u) / 256u);  // 16,384
    synth_semantic_kernel<<<dim3(blocks), dim3(256), 0, stream>>>(
        labels, id_int, id_dark, paren, outp);
}